// Round 9
// baseline (120.983 us; speedup 1.0000x reference)
//
#include <hip/hip_runtime.h>

#define F_   128
#define H_   16
#define E_   32
#define FG   8     // features per wave
#define BPW  64    // b rows per wave
#define WAVES 4
#define NTHREADS (WAVES * 64)   // 256
#define QB   16    // b's per quarter
#define NQ   (BPW / QB)         // 4

typedef float v2f __attribute__((ext_vector_type(2)));
typedef float v4f __attribute__((ext_vector_type(4)));

// R6 champion (55.0 us) with ONE isolated change: x loads hoisted into
// 16-deep batches, double-buffered in named registers (xA/xB, static
// indexing). Per quarter: issue 16 loads for the NEXT quarter, then 16x
// (compute + nt store) with ZERO memory waits inside. The only s_waitcnt
// per quarter is for the next x batch and sits behind 16 younger stores
// (vmcnt(16)) -> stores stay 16+ deep in flight instead of the champion's
// ~2 (whose per-iter prefetch forced vmcnt(1) = drain-all-but-one).
// Occupancy kept at 4 blocks/CU (R4's confound removed).
__global__ __launch_bounds__(NTHREADS, 4)
void nfe_kernel(const float* __restrict__ x,
                const float* __restrict__ W1,
                const float* __restrict__ b1,
                const float* __restrict__ W2,
                const float* __restrict__ b2,
                float* __restrict__ out)
{
    const int tid  = threadIdx.x;
    const int wave = tid >> 6;
    const int lane = tid & 63;

    const int f0 = blockIdx.x * FG;
    const int b0 = (blockIdx.y * WAVES + wave) * BPW;

    const int f  = f0 + (lane >> 3);
    const int e4 = lane & 7;

    // ---- per-lane weight fragments in registers (as f32 pairs) ----
    v2f w1p[H_/2], b1p[H_/2];
    {
        const v2f* p1 = (const v2f*)(W1 + f * H_);
        const v2f* p2 = (const v2f*)(b1 + f * H_);
#pragma unroll
        for (int q = 0; q < H_/2; ++q) { w1p[q] = p1[q]; b1p[q] = p2[q]; }
    }
    v2f w2p[H_][2];   // [j][e-pair], covers this lane's 4 e's
#pragma unroll
    for (int j = 0; j < H_; ++j) {
        const v2f* q = (const v2f*)(W2 + (f * H_ + j) * E_ + e4 * 4);
        w2p[j][0] = q[0]; w2p[j][1] = q[1];
    }
    v2f b2p[2];
    {
        const v2f* q = (const v2f*)(b2 + f * E_ + e4 * 4);
        b2p[0] = q[0]; b2p[1] = q[1];
    }

    const float* xp = x + (size_t)b0 * F_ + f;
    v4f* op = (v4f*)out + (size_t)b0 * (F_ * E_ / 4)
            + f0 * (E_ / 4) + lane;
    const int ostride = F_ * E_ / 4;   // v4f per b-row

    const v2f zero2 = {0.0f, 0.0f};

    float xA[QB], xB[QB];
#pragma unroll
    for (int k = 0; k < QB; ++k) xA[k] = xp[k * F_];

#define NFE_QTR(XCUR, XNXT, Q)                                               \
    do {                                                                     \
        if ((Q) + 1 < NQ) {                                                  \
            _Pragma("unroll")                                                \
            for (int k = 0; k < QB; ++k)                                     \
                XNXT[k] = xp[(((Q) + 1) * QB + k) * F_];                     \
        }                                                                    \
        __builtin_amdgcn_sched_barrier(0);                                   \
        _Pragma("unroll")                                                    \
        for (int k = 0; k < QB; ++k) {                                       \
            const float xv = XCUR[k];                                        \
            v2f x2 = {xv, xv};                                               \
            v2f h2[H_/2];                                                    \
            _Pragma("unroll")                                                \
            for (int q = 0; q < H_/2; ++q) {                                 \
                v2f t = __builtin_elementwise_fma(x2, w1p[q], b1p[q]);       \
                h2[q] = __builtin_elementwise_max(t, zero2);                 \
            }                                                                \
            v2f a0 = b2p[0], a1 = b2p[1];                                    \
            _Pragma("unroll")                                                \
            for (int q = 0; q < H_/2; ++q) {                                 \
                asm("v_pk_fma_f32 %0, %1, %2, %0 op_sel:[0,0,0] op_sel_hi:[0,1,1]" \
                    : "+v"(a0) : "v"(h2[q]), "v"(w2p[2*q][0]));              \
                asm("v_pk_fma_f32 %0, %1, %2, %0 op_sel:[0,0,0] op_sel_hi:[0,1,1]" \
                    : "+v"(a1) : "v"(h2[q]), "v"(w2p[2*q][1]));              \
                asm("v_pk_fma_f32 %0, %1, %2, %0 op_sel:[1,0,0] op_sel_hi:[1,1,1]" \
                    : "+v"(a0) : "v"(h2[q]), "v"(w2p[2*q+1][0]));            \
                asm("v_pk_fma_f32 %0, %1, %2, %0 op_sel:[1,0,0] op_sel_hi:[1,1,1]" \
                    : "+v"(a1) : "v"(h2[q]), "v"(w2p[2*q+1][1]));            \
            }                                                                \
            v4f acc = {a0.x, a0.y, a1.x, a1.y};                              \
            __builtin_nontemporal_store(acc, op + ((Q) * QB + k) * ostride); \
        }                                                                    \
    } while (0)

    NFE_QTR(xA, xB, 0);
    NFE_QTR(xB, xA, 1);
    NFE_QTR(xA, xB, 2);
    NFE_QTR(xB, xA, 3);
#undef NFE_QTR
}

extern "C" void kernel_launch(void* const* d_in, const int* in_sizes, int n_in,
                              void* d_out, int out_size, void* d_ws, size_t ws_size,
                              hipStream_t stream) {
    const float* x  = (const float*)d_in[0];
    const float* W1 = (const float*)d_in[1];
    const float* b1 = (const float*)d_in[2];
    const float* W2 = (const float*)d_in[3];
    const float* b2 = (const float*)d_in[4];
    float* out = (float*)d_out;

    const int B = in_sizes[0] / F_;                 // 16384
    dim3 grid(F_ / FG, B / (BPW * WAVES));          // (16, 64)
    nfe_kernel<<<grid, NTHREADS, 0, stream>>>(x, W1, b1, W2, b2, out);
}

// Round 10
// 58.251 us; speedup vs baseline: 2.0769x; 2.0769x over previous
//
#include <hip/hip_runtime.h>

#define F_   128
#define H_   16
#define E_   32
#define FG   8     // features per wave
#define BPW  64    // b rows per wave
#define WAVES 4
#define NTHREADS (WAVES * 64)   // 256
#define PF   4     // x prefetch distance (named rotation slots)

typedef float v2f __attribute__((ext_vector_type(2)));
typedef float v4f __attribute__((ext_vector_type(4)));

// R6 champion (55.0 us) with ONE isolated change: x prefetch distance 1 -> 4.
// xr[4] rotation slots, statically indexed inside an unrolled-by-4 body
// (+4 VGPRs, no macros, no sched_barrier -> regalloc stays healthy, unlike
// R8's VGPR=64 spill disaster). The awaited x load now sits behind ~7
// younger VMEM ops -> s_waitcnt vmcnt(~7) -> ~4 nt stores in flight per
// wave (vs ~2 with distance-1), i.e. ~64 KB/CU outstanding writes.
__global__ __launch_bounds__(NTHREADS, 4)
void nfe_kernel(const float* __restrict__ x,
                const float* __restrict__ W1,
                const float* __restrict__ b1,
                const float* __restrict__ W2,
                const float* __restrict__ b2,
                float* __restrict__ out)
{
    const int tid  = threadIdx.x;
    const int wave = tid >> 6;
    const int lane = tid & 63;

    const int f0 = blockIdx.x * FG;
    const int b0 = (blockIdx.y * WAVES + wave) * BPW;

    const int f  = f0 + (lane >> 3);
    const int e4 = lane & 7;

    // ---- per-lane weight fragments in registers (as f32 pairs) ----
    v2f w1p[H_/2], b1p[H_/2];
    {
        const v2f* p1 = (const v2f*)(W1 + f * H_);
        const v2f* p2 = (const v2f*)(b1 + f * H_);
#pragma unroll
        for (int q = 0; q < H_/2; ++q) { w1p[q] = p1[q]; b1p[q] = p2[q]; }
    }
    v2f w2p[H_][2];   // [j][e-pair], covers this lane's 4 e's
#pragma unroll
    for (int j = 0; j < H_; ++j) {
        const v2f* q = (const v2f*)(W2 + (f * H_ + j) * E_ + e4 * 4);
        w2p[j][0] = q[0]; w2p[j][1] = q[1];
    }
    v2f b2p[2];
    {
        const v2f* q = (const v2f*)(b2 + f * E_ + e4 * 4);
        b2p[0] = q[0]; b2p[1] = q[1];
    }

    // ---- streaming loop over b ----
    const float* xp = x + (size_t)b0 * F_ + f;
    v4f* op = (v4f*)out + (size_t)b0 * (F_ * E_ / 4)
            + f0 * (E_ / 4) + lane;
    const int ostride = F_ * E_ / 4;   // v4f per b-row

    const v2f zero2 = {0.0f, 0.0f};

    float xr[PF];
#pragma unroll
    for (int k = 0; k < PF; ++k) xr[k] = xp[k * F_];

    int ii = 0;
    for (; ii < BPW - PF; ii += PF) {
#pragma unroll
        for (int k = 0; k < PF; ++k) {
            const float xv = xr[k];
            xr[k] = xp[(ii + PF + k) * F_];   // load for iter ii+PF+k

            v2f x2 = {xv, xv};
            v2f h2[H_/2];
#pragma unroll
            for (int q = 0; q < H_/2; ++q) {
                v2f t = __builtin_elementwise_fma(x2, w1p[q], b1p[q]);
                h2[q] = __builtin_elementwise_max(t, zero2);
            }
            v2f a0 = b2p[0], a1 = b2p[1];
#pragma unroll
            for (int q = 0; q < H_/2; ++q) {
                asm("v_pk_fma_f32 %0, %1, %2, %0 op_sel:[0,0,0] op_sel_hi:[0,1,1]"
                    : "+v"(a0) : "v"(h2[q]), "v"(w2p[2*q][0]));
                asm("v_pk_fma_f32 %0, %1, %2, %0 op_sel:[0,0,0] op_sel_hi:[0,1,1]"
                    : "+v"(a1) : "v"(h2[q]), "v"(w2p[2*q][1]));
                asm("v_pk_fma_f32 %0, %1, %2, %0 op_sel:[1,0,0] op_sel_hi:[1,1,1]"
                    : "+v"(a0) : "v"(h2[q]), "v"(w2p[2*q+1][0]));
                asm("v_pk_fma_f32 %0, %1, %2, %0 op_sel:[1,0,0] op_sel_hi:[1,1,1]"
                    : "+v"(a1) : "v"(h2[q]), "v"(w2p[2*q+1][1]));
            }
            v4f acc = {a0.x, a0.y, a1.x, a1.y};
            __builtin_nontemporal_store(acc, op + (ii + k) * ostride);
        }
    }
    // epilogue: last PF iterations, no further loads
#pragma unroll
    for (int k = 0; k < PF; ++k) {
        const float xv = xr[k];
        v2f x2 = {xv, xv};
        v2f h2[H_/2];
#pragma unroll
        for (int q = 0; q < H_/2; ++q) {
            v2f t = __builtin_elementwise_fma(x2, w1p[q], b1p[q]);
            h2[q] = __builtin_elementwise_max(t, zero2);
        }
        v2f a0 = b2p[0], a1 = b2p[1];
#pragma unroll
        for (int q = 0; q < H_/2; ++q) {
            asm("v_pk_fma_f32 %0, %1, %2, %0 op_sel:[0,0,0] op_sel_hi:[0,1,1]"
                : "+v"(a0) : "v"(h2[q]), "v"(w2p[2*q][0]));
            asm("v_pk_fma_f32 %0, %1, %2, %0 op_sel:[0,0,0] op_sel_hi:[0,1,1]"
                : "+v"(a1) : "v"(h2[q]), "v"(w2p[2*q][1]));
            asm("v_pk_fma_f32 %0, %1, %2, %0 op_sel:[1,0,0] op_sel_hi:[1,1,1]"
                : "+v"(a0) : "v"(h2[q]), "v"(w2p[2*q+1][0]));
            asm("v_pk_fma_f32 %0, %1, %2, %0 op_sel:[1,0,0] op_sel_hi:[1,1,1]"
                : "+v"(a1) : "v"(h2[q]), "v"(w2p[2*q+1][1]));
        }
        v4f acc = {a0.x, a0.y, a1.x, a1.y};
        __builtin_nontemporal_store(acc, op + (BPW - PF + k) * ostride);
    }
}

extern "C" void kernel_launch(void* const* d_in, const int* in_sizes, int n_in,
                              void* d_out, int out_size, void* d_ws, size_t ws_size,
                              hipStream_t stream) {
    const float* x  = (const float*)d_in[0];
    const float* W1 = (const float*)d_in[1];
    const float* b1 = (const float*)d_in[2];
    const float* W2 = (const float*)d_in[3];
    const float* b2 = (const float*)d_in[4];
    float* out = (float*)d_out;

    const int B = in_sizes[0] / F_;                 // 16384
    dim3 grid(F_ / FG, B / (BPW * WAVES));          // (16, 64)
    nfe_kernel<<<grid, NTHREADS, 0, stream>>>(x, W1, b1, W2, b2, out);
}